// Round 1
// baseline (10956.764 us; speedup 1.0000x reference)
//
#include <hip/hip_runtime.h>
#include <cfloat>
#include <cstdint>

#define VOCABN 32000
#define EMBN   256
#define HIDN   512
#define LATN   128
#define BN     16
#define TN     128
#define NPART  500   // VOCABN / 64
#define H2PAD  516   // 512 + 4 pad to dodge LDS bank conflicts

// ---------------------------------------------------------------------------
// zero helpers
// ---------------------------------------------------------------------------
__global__ void zero_buf(float* __restrict__ p, int n) {
    int i = blockIdx.x * blockDim.x + threadIdx.x;
    if (i < n) p[i] = 0.f;
}

// outputs[:, 0, :] = 0   (16 rows of 32000 floats, stride T*V)
__global__ void zero_out_t0(float* __restrict__ out) {
    int i = blockIdx.x * blockDim.x + threadIdx.x;   // 128000 threads, float4 each
    if (i >= (BN * VOCABN) / 4) return;
    int b  = i / (VOCABN / 4);
    int v4 = (i % (VOCABN / 4)) * 4;
    float4 zz = make_float4(0.f, 0.f, 0.f, 0.f);
    *(float4*)&out[(size_t)b * (TN * (size_t)VOCABN) + v4] = zz;
}

// ---------------------------------------------------------------------------
// One GRU step.  grid = 128 blocks (16 b x 8 i-chunks), 256 threads.
// Thread = (out_local 0..63, ks 0..3): k-split x4, shfl reduce.
// MODE 0: encoder, token = x[b, t]
// MODE 1: decoder first step, token = x[b, 0]
// MODE 2: decoder, token = argmax over NPART partials (first-index tie-break)
// ---------------------------------------------------------------------------
template <int MODE>
__launch_bounds__(256)
__global__ void gru_step(const int* __restrict__ x, int t,
                         const float* __restrict__ emb,
                         const float* __restrict__ Wih, const float* __restrict__ Whh,
                         const float* __restrict__ bih, const float* __restrict__ bhh,
                         const float* __restrict__ h_in, float* __restrict__ h_out,
                         const float* __restrict__ pval, const int* __restrict__ pidx)
{
    __shared__ float e_lds[EMBN];
    __shared__ float h_lds[HIDN];
    __shared__ float rv[256];
    __shared__ int   ri[256];
    __shared__ int   tok_sh;

    const int tid = threadIdx.x;
    const int b   = blockIdx.x >> 3;
    const int ic  = blockIdx.x & 7;

    int tok;
    if (MODE == 0) {
        tok = x[b * TN + t];
    } else if (MODE == 1) {
        tok = x[b * TN];
    } else {
        // reduce argmax partials for batch b (val desc, idx asc tie-break)
        float bv = -FLT_MAX; int bi = 0x7fffffff;
        for (int e = tid; e < NPART; e += 256) {
            float v  = pval[e * BN + b];
            int   ix = pidx[e * BN + b];
            if (v > bv || (v == bv && ix < bi)) { bv = v; bi = ix; }
        }
        rv[tid] = bv; ri[tid] = bi;
        __syncthreads();
        for (int s = 128; s > 0; s >>= 1) {
            if (tid < s) {
                float ov = rv[tid + s]; int oi = ri[tid + s];
                if (ov > rv[tid] || (ov == rv[tid] && oi < ri[tid])) { rv[tid] = ov; ri[tid] = oi; }
            }
            __syncthreads();
        }
        if (tid == 0) tok_sh = ri[0];
        __syncthreads();
        tok = tok_sh;
    }

    // stage embedding row + h row
    e_lds[tid]           = emb[(size_t)tok * EMBN + tid];
    h_lds[tid]           = h_in[b * HIDN + tid];
    h_lds[tid + 256]     = h_in[b * HIDN + tid + 256];
    __syncthreads();

    const int ol = tid >> 2;          // 0..63
    const int ks = tid & 3;           // k-split
    const int i  = ic * 64 + ol;      // hidden index 0..511

    float gi[3] = {0.f, 0.f, 0.f};
    float gh[3] = {0.f, 0.f, 0.f};

    {
        const int k0 = ks * 64;
        const float4* e4 = (const float4*)&e_lds[k0];
#pragma unroll
        for (int g = 0; g < 3; ++g) {
            const float4* w4 = (const float4*)&Wih[(size_t)(g * HIDN + i) * EMBN + k0];
            float s = 0.f;
#pragma unroll
            for (int kk = 0; kk < 16; ++kk) {
                float4 w = w4[kk], e = e4[kk];
                s += w.x * e.x + w.y * e.y + w.z * e.z + w.w * e.w;
            }
            gi[g] = s;
        }
    }
    {
        const int k0 = ks * 128;
        const float4* h4 = (const float4*)&h_lds[k0];
#pragma unroll
        for (int g = 0; g < 3; ++g) {
            const float4* w4 = (const float4*)&Whh[(size_t)(g * HIDN + i) * HIDN + k0];
            float s = 0.f;
#pragma unroll
            for (int kk = 0; kk < 32; ++kk) {
                float4 w = w4[kk], h = h4[kk];
                s += w.x * h.x + w.y * h.y + w.z * h.z + w.w * h.w;
            }
            gh[g] = s;
        }
    }

#pragma unroll
    for (int g = 0; g < 3; ++g) {
        gi[g] += __shfl_xor(gi[g], 1); gi[g] += __shfl_xor(gi[g], 2);
        gh[g] += __shfl_xor(gh[g], 1); gh[g] += __shfl_xor(gh[g], 2);
    }

    if (ks == 0) {
        float ir  = gi[0] + bih[i];
        float iz  = gi[1] + bih[HIDN + i];
        float in_ = gi[2] + bih[2 * HIDN + i];
        float hr  = gh[0] + bhh[i];
        float hz  = gh[1] + bhh[HIDN + i];
        float hn  = gh[2] + bhh[2 * HIDN + i];
        float r  = 1.f / (1.f + expf(-(ir + hr)));
        float zg = 1.f / (1.f + expf(-(iz + hz)));
        float n  = tanhf(in_ + r * hn);
        h_out[b * HIDN + i] = (1.f - zg) * n + zg * h_lds[i];
    }
}

// ---------------------------------------------------------------------------
// logits = h2 @ fc_out_W.T + b; write out[:, t, :]; per-block argmax partials.
// grid = 500 blocks x 256 threads. Block covers 64 v x all 16 b.
// Wave = 16 b x 4 vg; thread = (vg, b) owns 4 consecutive v, 1 b.
// Lanes sharing vg read identical W addresses -> broadcast-merged: W read 1x.
// ---------------------------------------------------------------------------
__launch_bounds__(256)
__global__ void logits_step(const float* __restrict__ h2,
                            const float* __restrict__ Wout, const float* __restrict__ bout,
                            float* __restrict__ out, int t,
                            float* __restrict__ pval, int* __restrict__ pidx)
{
    __shared__ float h2s[BN * H2PAD];
    __shared__ float wval[4][16];
    __shared__ int   widx[4][16];

    const int tid = threadIdx.x;

    // stage h2 (16x512) into padded LDS, float4 coalesced
    for (int idx = tid; idx < (BN * HIDN) / 4; idx += 256) {
        int bb = idx >> 7, k4 = idx & 127;
        float4 v = *(const float4*)&h2[bb * HIDN + k4 * 4];
        *(float4*)&h2s[bb * H2PAD + k4 * 4] = v;
    }
    __syncthreads();

    const int wv   = tid >> 6;
    const int lane = tid & 63;
    const int vg   = lane >> 4;
    const int b    = lane & 15;
    const int v0   = blockIdx.x * 64 + wv * 16 + vg * 4;

    float a0 = 0.f, a1 = 0.f, a2 = 0.f, a3 = 0.f;
    const float4* w0 = (const float4*)&Wout[(size_t)(v0 + 0) * HIDN];
    const float4* w1 = (const float4*)&Wout[(size_t)(v0 + 1) * HIDN];
    const float4* w2 = (const float4*)&Wout[(size_t)(v0 + 2) * HIDN];
    const float4* w3 = (const float4*)&Wout[(size_t)(v0 + 3) * HIDN];
    const float4* hh = (const float4*)&h2s[b * H2PAD];

#pragma unroll 4
    for (int k4 = 0; k4 < HIDN / 4; ++k4) {
        float4 h4 = hh[k4];
        float4 q0 = w0[k4]; a0 += q0.x * h4.x + q0.y * h4.y + q0.z * h4.z + q0.w * h4.w;
        float4 q1 = w1[k4]; a1 += q1.x * h4.x + q1.y * h4.y + q1.z * h4.z + q1.w * h4.w;
        float4 q2 = w2[k4]; a2 += q2.x * h4.x + q2.y * h4.y + q2.z * h4.z + q2.w * h4.w;
        float4 q3 = w3[k4]; a3 += q3.x * h4.x + q3.y * h4.y + q3.z * h4.z + q3.w * h4.w;
    }

    a0 += bout[v0 + 0];
    a1 += bout[v0 + 1];
    a2 += bout[v0 + 2];
    a3 += bout[v0 + 3];

    *(float4*)&out[(size_t)b * (TN * (size_t)VOCABN) + (size_t)t * VOCABN + v0] =
        make_float4(a0, a1, a2, a3);

    // thread-local argmax (ascending v, strict > keeps first index)
    float bv = a0; int bi = v0;
    if (a1 > bv) { bv = a1; bi = v0 + 1; }
    if (a2 > bv) { bv = a2; bi = v0 + 2; }
    if (a3 > bv) { bv = a3; bi = v0 + 3; }

    // reduce across vg (lanes differ by 16, 32 — same b)
#pragma unroll
    for (int m = 16; m <= 32; m <<= 1) {
        float ov = __shfl_xor(bv, m);
        int   oi = __shfl_xor(bi, m);
        if (ov > bv || (ov == bv && oi < bi)) { bv = ov; bi = oi; }
    }
    if (vg == 0) { wval[wv][b] = bv; widx[wv][b] = bi; }
    __syncthreads();
    if (tid < 16) {
        float fv = wval[0][tid]; int fi = widx[0][tid];
#pragma unroll
        for (int w = 1; w < 4; ++w) {
            float ov = wval[w][tid]; int oi = widx[w][tid];
            if (ov > fv || (ov == fv && oi < fi)) { fv = ov; fi = oi; }
        }
        pval[blockIdx.x * BN + tid] = fv;
        pidx[blockIdx.x * BN + tid] = fi;
    }
}

// ---------------------------------------------------------------------------
// z = h_enc @ fc_enc_W.T + b   (16 x 128), write to ws zbuf and out tail
// ---------------------------------------------------------------------------
__launch_bounds__(128)
__global__ void z_step(const float* __restrict__ h, const float* __restrict__ W,
                       const float* __restrict__ bias,
                       float* __restrict__ zbuf, float* __restrict__ out_z)
{
    __shared__ float hs[HIDN];
    const int tid = threadIdx.x, b = blockIdx.x;
    hs[tid]       = h[b * HIDN + tid];
    hs[tid + 128] = h[b * HIDN + tid + 128];
    hs[tid + 256] = h[b * HIDN + tid + 256];
    hs[tid + 384] = h[b * HIDN + tid + 384];
    __syncthreads();
    float s = 0.f;
    const float4* w4 = (const float4*)&W[(size_t)tid * HIDN];
    const float4* h4 = (const float4*)hs;
#pragma unroll 4
    for (int k = 0; k < HIDN / 4; ++k) {
        float4 w = w4[k], hv = h4[k];
        s += w.x * hv.x + w.y * hv.y + w.z * hv.z + w.w * hv.w;
    }
    s += bias[tid];
    zbuf[b * LATN + tid]  = s;
    out_z[b * LATN + tid] = s;
}

// ---------------------------------------------------------------------------
// hid = tanh(z @ fc_dec_W.T + b)   (16 x 512)
// ---------------------------------------------------------------------------
__launch_bounds__(256)
__global__ void hid_step(const float* __restrict__ z, const float* __restrict__ W,
                         const float* __restrict__ bias, float* __restrict__ h0)
{
    __shared__ float zs[LATN];
    const int tid  = threadIdx.x;
    const int b    = blockIdx.x >> 1;
    const int half = blockIdx.x & 1;
    if (tid < LATN) zs[tid] = z[b * LATN + tid];
    __syncthreads();
    const int i = half * 256 + tid;
    float s = 0.f;
    const float4* w4 = (const float4*)&W[(size_t)i * LATN];
    const float4* z4 = (const float4*)zs;
#pragma unroll
    for (int k = 0; k < LATN / 4; ++k) {
        float4 w = w4[k], zz = z4[k];
        s += w.x * zz.x + w.y * zz.y + w.z * zz.z + w.w * zz.w;
    }
    h0[b * HIDN + i] = tanhf(s + bias[i]);
}

// ---------------------------------------------------------------------------
extern "C" void kernel_launch(void* const* d_in, const int* in_sizes, int n_in,
                              void* d_out, int out_size, void* d_ws, size_t ws_size,
                              hipStream_t stream)
{
    const int*   x        = (const int*)  d_in[0];
    const float* emb_enc  = (const float*)d_in[1];
    const float* enc_Wih  = (const float*)d_in[2];
    const float* enc_Whh  = (const float*)d_in[3];
    const float* enc_bih  = (const float*)d_in[4];
    const float* enc_bhh  = (const float*)d_in[5];
    const float* fc_enc_W = (const float*)d_in[6];
    const float* fc_enc_b = (const float*)d_in[7];
    const float* fc_dec_W = (const float*)d_in[8];
    const float* fc_dec_b = (const float*)d_in[9];
    const float* emb_dec  = (const float*)d_in[10];
    const float* dec_Wih  = (const float*)d_in[11];
    const float* dec_Whh  = (const float*)d_in[12];
    const float* dec_bih  = (const float*)d_in[13];
    const float* dec_bhh  = (const float*)d_in[14];
    const float* fc_out_W = (const float*)d_in[15];
    const float* fc_out_b = (const float*)d_in[16];

    float* out = (float*)d_out;
    float* ws  = (float*)d_ws;

    float* henc0 = ws;
    float* henc1 = henc0 + BN * HIDN;
    float* hdec0 = henc1 + BN * HIDN;
    float* hdec1 = hdec0 + BN * HIDN;
    float* zbuf  = hdec1 + BN * HIDN;
    float* pval  = zbuf + BN * LATN;
    int*   pidx  = (int*)(pval + NPART * BN);

    float* out_z = out + (size_t)BN * TN * VOCABN;

    // init: h_enc = 0, outputs[:,0,:] = 0
    zero_buf<<<32, 256, 0, stream>>>(henc0, BN * HIDN);
    zero_out_t0<<<500, 256, 0, stream>>>(out);

    // encoder recurrence (final h lands in henc0 since TN is even)
    for (int t = 0; t < TN; ++t) {
        const float* hi = (t & 1) ? henc1 : henc0;
        float*       ho = (t & 1) ? henc0 : henc1;
        gru_step<0><<<128, 256, 0, stream>>>(x, t, emb_enc, enc_Wih, enc_Whh,
                                             enc_bih, enc_bhh, hi, ho, nullptr, nullptr);
    }

    z_step<<<BN, 128, 0, stream>>>(henc0, fc_enc_W, fc_enc_b, zbuf, out_z);
    hid_step<<<32, 256, 0, stream>>>(zbuf, fc_dec_W, fc_dec_b, hdec0);

    // decoder: 127 steps, logits written to out[:, s+1, :]
    for (int s = 0; s < TN - 1; ++s) {
        const float* hi = (s & 1) ? hdec1 : hdec0;
        float*       ho = (s & 1) ? hdec0 : hdec1;
        if (s == 0)
            gru_step<1><<<128, 256, 0, stream>>>(x, 0, emb_dec, dec_Wih, dec_Whh,
                                                 dec_bih, dec_bhh, hi, ho, nullptr, nullptr);
        else
            gru_step<2><<<128, 256, 0, stream>>>(x, 0, emb_dec, dec_Wih, dec_Whh,
                                                 dec_bih, dec_bhh, hi, ho, pval, pidx);
        logits_step<<<NPART, 256, 0, stream>>>(ho, fc_out_W, fc_out_b, out, s + 1, pval, pidx);
    }
}